// Round 1
// baseline (3224.165 us; speedup 1.0000x reference)
//
#include <hip/hip_runtime.h>
#include <math.h>

#define NLOC 4096
#define NREP 128
#define MN   48
#define XSS  49   // xs LDS row stride (odd -> conflict-free strided row reads)

// One block per location. 256 threads; thread (ti,tj) owns an 8x8 register
// tile: rows i = ti*8 + r (r=0..7), cols j = tj*4 + 64*g + e (g=0..1, e=0..3).
__global__ __launch_bounds__(256, 2)
void otm_fused(const float* __restrict__ aug,
               const float* __restrict__ theta,
               const float* __restrict__ scales,
               const float* __restrict__ nug_mean,
               const int*   __restrict__ batch_idx,
               float* __restrict__ out_g,
               float* __restrict__ out_l)
{
    __shared__ float xs[NREP * XSS];     // 25088 B
    __shared__ float ldiag[NREP];
    __shared__ float scal_s[MN];
    __shared__ float col[2][NREP];       // pivot column double-buffer
    __shared__ float rs[NREP];           // 1/sqrt(c_k) per column

    const int loc = blockIdx.x;
    const int tid = threadIdx.x;
    const int ti  = tid >> 4;
    const int tj  = tid & 15;
    const int i0  = ti << 3;   // first owned row
    const int j00 = tj << 2;   // base owned col

    // --- per-k feature scaling: scal[k] = sqrt(exp(-(k+1)*exp(theta2))) ---
    const float th2 = theta[2];
    if (tid < MN) {
        float e2 = expf(th2);
        scal_s[tid] = expf(-0.5f * (float)(tid + 1) * e2);
    }
    __syncthreads();

    // --- gather aug[:,loc,1:49], NaN->0, scale, into LDS (row-major) ---
    for (int idx = tid; idx < NREP * MN; idx += 256) {
        int r = idx / MN;
        int c = idx - r * MN;
        float v = aug[(r * NLOC + loc) * (MN + 1) + 1 + c];
        v = (v != v) ? 0.0f : v;
        xs[r * XSS + c] = v * scal_s[c];
    }
    __syncthreads();

    // --- row norms (diagonal of Gram), threads 0..127 ---
    if (tid < NREP) {
        float s = 0.0f;
        #pragma unroll
        for (int kk = 0; kk < MN; ++kk) {
            float v = xs[tid * XSS + kk];
            s = fmaf(v, v, s);
        }
        ldiag[tid] = s;
    }

    // --- Gram: acc[r][c] = sum_k xs[i][k]*xs[j][k] ---
    float acc[8][8];
    #pragma unroll
    for (int r = 0; r < 8; ++r)
        #pragma unroll
        for (int c = 0; c < 8; ++c) acc[r][c] = 0.0f;

    for (int kk = 0; kk < MN; ++kk) {
        float a[8], b[8];
        #pragma unroll
        for (int r = 0; r < 8; ++r) a[r] = xs[(i0 + r) * XSS + kk];
        #pragma unroll
        for (int g = 0; g < 2; ++g)
            #pragma unroll
            for (int e = 0; e < 4; ++e)
                b[g * 4 + e] = xs[(j00 + 64 * g + e) * XSS + kk];
        #pragma unroll
        for (int r = 0; r < 8; ++r)
            #pragma unroll
            for (int c = 0; c < 8; ++c)
                acc[r][c] = fmaf(a[r], b[c], acc[r][c]);
    }
    __syncthreads();   // ldiag ready

    // --- elementwise transform: G = (lin + sig2*matern)/nug + I ---
    const float s_loc   = scales[loc];
    const float th3 = theta[3], th4 = theta[4], th5 = theta[5];
    const float sig2    = expf(2.0f * fmaf(logf(s_loc), th4, th3));
    const float nug_inv = 1.0f / nug_mean[loc];
    const float ls      = expf(th5) * 1.7320508075688772f;  // sqrt(2*1.5)
    const float inv_ls2 = 1.0f / (ls * ls);
    const bool  is0     = (batch_idx[loc] == 0);

    float di[8], dj[8];
    #pragma unroll
    for (int r = 0; r < 8; ++r) di[r] = ldiag[i0 + r];
    #pragma unroll
    for (int g = 0; g < 2; ++g)
        #pragma unroll
        for (int e = 0; e < 4; ++e) dj[g * 4 + e] = ldiag[j00 + 64 * g + e];

    float* gout = out_g + (size_t)loc * (NREP * NREP);
    #pragma unroll
    for (int r = 0; r < 8; ++r) {
        const int i = i0 + r;
        #pragma unroll
        for (int g = 0; g < 2; ++g) {
            float tmp[4];
            #pragma unroll
            for (int e = 0; e < 4; ++e) {
                const int c = g * 4 + e;
                const int j = j00 + 64 * g + e;
                float lin = acc[r][c];
                float sq  = (di[r] + dj[c] - 2.0f * lin) * inv_ls2;
                sq = fmaxf(sq, 0.0f);
                float d3  = 1.7320508075688772f * sqrtf(sq);
                float mat = (1.0f + d3) * __expf(-d3);
                float gv  = fmaf(sig2, mat, lin) * nug_inv + ((i == j) ? 1.0f : 0.0f);
                if (is0) gv = (i == j) ? 1.0f : 0.0f;
                acc[r][c] = gv;
                tmp[e] = gv;
            }
            float4 v = make_float4(tmp[0], tmp[1], tmp[2], tmp[3]);
            *(float4*)(gout + (size_t)i * NREP + j00 + 64 * g) = v;
        }
    }

    // --- Cholesky, unnormalized-column right-looking, acc in registers ---
    // Invariant: after iteration k, entry (i,j) with j<=k holds c = L[i][j]*L[j][j].
    if (tj == 0) {
        #pragma unroll
        for (int r = 0; r < 8; ++r) col[0][i0 + r] = acc[r][0];
    }
    __syncthreads();

    for (int k = 0; k < NREP; ++k) {
        const float* cur = col[k & 1];
        const float ck   = cur[k];
        const float dinv = 1.0f / ck;
        if (tid == 0) rs[k] = 1.0f / sqrtf(ck);

        float ci[8], cj[8];
        #pragma unroll
        for (int r = 0; r < 8; ++r) ci[r] = cur[i0 + r];
        #pragma unroll
        for (int g = 0; g < 2; ++g)
            #pragma unroll
            for (int e = 0; e < 4; ++e) cj[g * 4 + e] = cur[j00 + 64 * g + e];

        if (i0 + 7 > k) {                        // whole tile-row inactive -> skip
            #pragma unroll
            for (int r = 0; r < 8; ++r) {
                const int i = i0 + r;
                if (i > k) {
                    const float fir = ci[r] * dinv;
                    #pragma unroll
                    for (int g = 0; g < 2; ++g)
                        #pragma unroll
                        for (int e = 0; e < 4; ++e) {
                            const int c = g * 4 + e;
                            const int j = j00 + 64 * g + e;
                            if (j > k) acc[r][c] = fmaf(-fir, cj[c], acc[r][c]);
                        }
                }
            }
        }

        // publish column k+1 (already updated above) into the other buffer
        const int kn = k + 1;
        if (kn < NREP && ((kn >> 2) & 15) == tj) {
            const int c = ((kn >> 6) << 2) | (kn & 3);
            float* nxt = col[kn & 1];
            #pragma unroll
            for (int r = 0; r < 8; ++r) nxt[i0 + r] = acc[r][c];
        }
        __syncthreads();
    }

    // --- epilogue: L[i][j] = c_ij / sqrt(c_jj), zeros above diagonal ---
    float* lout = out_l + (size_t)loc * (NREP * NREP);
    #pragma unroll
    for (int r = 0; r < 8; ++r) {
        const int i = i0 + r;
        #pragma unroll
        for (int g = 0; g < 2; ++g) {
            float tmp[4];
            #pragma unroll
            for (int e = 0; e < 4; ++e) {
                const int j = j00 + 64 * g + e;
                const int c = g * 4 + e;
                tmp[e] = (i >= j) ? acc[r][c] * rs[j] : 0.0f;
            }
            float4 v = make_float4(tmp[0], tmp[1], tmp[2], tmp[3]);
            *(float4*)(lout + (size_t)i * NREP + j00 + 64 * g) = v;
        }
    }
}

extern "C" void kernel_launch(void* const* d_in, const int* in_sizes, int n_in,
                              void* d_out, int out_size, void* d_ws, size_t ws_size,
                              hipStream_t stream) {
    const float* aug    = (const float*)d_in[0];
    const float* theta  = (const float*)d_in[1];
    const float* scales = (const float*)d_in[2];
    const float* nug    = (const float*)d_in[3];
    const int*   bidx   = (const int*)d_in[4];
    float* g = (float*)d_out;
    float* l = g + (size_t)NLOC * NREP * NREP;
    hipLaunchKernelGGL(otm_fused, dim3(NLOC), dim3(256), 0, stream,
                       aug, theta, scales, nug, bidx, g, l);
}

// Round 2
// 1718.949 us; speedup vs baseline: 1.8757x; 1.8757x over previous
//
#include <hip/hip_runtime.h>
#include <math.h>

#define NLOC 4096
#define NREP 128
#define MN   48
#define XSS  49   // xs LDS row stride (odd -> conflict-free strided row reads)

// One block per location. 256 threads; thread (ti,tj) owns an 8x8 register
// tile: rows i = ti*8 + r (r=0..7), cols j = tj*4 + 64*g + e (g=0..1, e=0..3).
// NOTE: acc[][] must NEVER be indexed with a runtime value -> scratch demotion
// (R1: VGPR=68, 13 GB scratch writes, 2.9 ms). All accesses are unrolled-const;
// the pivot-column publish uses a cndmask selection chain instead.
__global__ __launch_bounds__(256, 2)
void otm_fused(const float* __restrict__ aug,
               const float* __restrict__ theta,
               const float* __restrict__ scales,
               const float* __restrict__ nug_mean,
               const int*   __restrict__ batch_idx,
               float* __restrict__ out_g,
               float* __restrict__ out_l)
{
    __shared__ float xs[NREP * XSS];     // 25088 B
    __shared__ float ldiag[NREP];
    __shared__ float scal_s[MN];
    __shared__ float col[2][NREP];       // pivot column double-buffer
    __shared__ float rs[NREP];           // 1/sqrt(c_k) per column

    const int loc = blockIdx.x;
    const int tid = threadIdx.x;
    const int ti  = tid >> 4;
    const int tj  = tid & 15;
    const int i0  = ti << 3;   // first owned row
    const int j00 = tj << 2;   // base owned col

    // --- per-k feature scaling: scal[k] = sqrt(exp(-(k+1)*exp(theta2))) ---
    const float th2 = theta[2];
    if (tid < MN) {
        float e2 = expf(th2);
        scal_s[tid] = expf(-0.5f * (float)(tid + 1) * e2);
    }
    __syncthreads();

    // --- gather aug[:,loc,1:49], NaN->0, scale, into LDS (row-major) ---
    for (int idx = tid; idx < NREP * MN; idx += 256) {
        int r = idx / MN;
        int c = idx - r * MN;
        float v = aug[(r * NLOC + loc) * (MN + 1) + 1 + c];
        v = (v != v) ? 0.0f : v;
        xs[r * XSS + c] = v * scal_s[c];
    }
    __syncthreads();

    // --- row norms (diagonal of Gram), threads 0..127 ---
    if (tid < NREP) {
        float s = 0.0f;
        #pragma unroll
        for (int kk = 0; kk < MN; ++kk) {
            float v = xs[tid * XSS + kk];
            s = fmaf(v, v, s);
        }
        ldiag[tid] = s;
    }

    // --- Gram: acc[r][c] = sum_k xs[i][k]*xs[j][k] ---
    float acc[8][8];
    #pragma unroll
    for (int r = 0; r < 8; ++r)
        #pragma unroll
        for (int c = 0; c < 8; ++c) acc[r][c] = 0.0f;

    for (int kk = 0; kk < MN; ++kk) {
        float a[8], b[8];
        #pragma unroll
        for (int r = 0; r < 8; ++r) a[r] = xs[(i0 + r) * XSS + kk];
        #pragma unroll
        for (int g = 0; g < 2; ++g)
            #pragma unroll
            for (int e = 0; e < 4; ++e)
                b[g * 4 + e] = xs[(j00 + 64 * g + e) * XSS + kk];
        #pragma unroll
        for (int r = 0; r < 8; ++r)
            #pragma unroll
            for (int c = 0; c < 8; ++c)
                acc[r][c] = fmaf(a[r], b[c], acc[r][c]);
    }
    __syncthreads();   // ldiag ready

    // --- elementwise transform: G = (lin + sig2*matern)/nug + I ---
    const float s_loc   = scales[loc];
    const float th3 = theta[3], th4 = theta[4], th5 = theta[5];
    const float sig2    = expf(2.0f * fmaf(logf(s_loc), th4, th3));
    const float nug_inv = 1.0f / nug_mean[loc];
    const float ls      = expf(th5) * 1.7320508075688772f;  // sqrt(2*1.5)
    const float inv_ls2 = 1.0f / (ls * ls);
    const bool  is0     = (batch_idx[loc] == 0);

    float di[8], dj[8];
    #pragma unroll
    for (int r = 0; r < 8; ++r) di[r] = ldiag[i0 + r];
    #pragma unroll
    for (int g = 0; g < 2; ++g)
        #pragma unroll
        for (int e = 0; e < 4; ++e) dj[g * 4 + e] = ldiag[j00 + 64 * g + e];

    float* gout = out_g + (size_t)loc * (NREP * NREP);
    #pragma unroll
    for (int r = 0; r < 8; ++r) {
        const int i = i0 + r;
        #pragma unroll
        for (int g = 0; g < 2; ++g) {
            float tmp[4];
            #pragma unroll
            for (int e = 0; e < 4; ++e) {
                const int c = g * 4 + e;
                const int j = j00 + 64 * g + e;
                float lin = acc[r][c];
                float sq  = (di[r] + dj[c] - 2.0f * lin) * inv_ls2;
                sq = fmaxf(sq, 0.0f);
                float d3  = 1.7320508075688772f * sqrtf(sq);
                float mat = (1.0f + d3) * __expf(-d3);
                float gv  = fmaf(sig2, mat, lin) * nug_inv + ((i == j) ? 1.0f : 0.0f);
                if (is0) gv = (i == j) ? 1.0f : 0.0f;
                acc[r][c] = gv;
                tmp[e] = gv;
            }
            float4 v = make_float4(tmp[0], tmp[1], tmp[2], tmp[3]);
            *(float4*)(gout + (size_t)i * NREP + j00 + 64 * g) = v;
        }
    }

    // --- Cholesky, unnormalized-column right-looking, acc in registers ---
    // Invariant: after iteration k, entry (i,j) with j<=k holds c = L[i][j]*L[j][j].
    if (tj == 0) {
        #pragma unroll
        for (int r = 0; r < 8; ++r) col[0][i0 + r] = acc[r][0];
    }
    __syncthreads();

    for (int k = 0; k < NREP; ++k) {
        const float* cur = col[k & 1];
        const float ck   = cur[k];
        const float dinv = 1.0f / ck;
        if (tid == 0) rs[k] = 1.0f / sqrtf(ck);

        float ci[8], cj[8];
        #pragma unroll
        for (int r = 0; r < 8; ++r) ci[r] = cur[i0 + r];
        #pragma unroll
        for (int g = 0; g < 2; ++g)
            #pragma unroll
            for (int e = 0; e < 4; ++e) cj[g * 4 + e] = cur[j00 + 64 * g + e];

        if (i0 + 7 > k) {                        // whole tile-row inactive -> skip
            #pragma unroll
            for (int r = 0; r < 8; ++r) {
                const int i = i0 + r;
                if (i > k) {
                    const float fir = ci[r] * dinv;
                    #pragma unroll
                    for (int g = 0; g < 2; ++g)
                        #pragma unroll
                        for (int e = 0; e < 4; ++e) {
                            const int c = g * 4 + e;
                            const int j = j00 + 64 * g + e;
                            if (j > k) acc[r][c] = fmaf(-fir, cj[c], acc[r][c]);
                        }
                }
            }
        }

        // publish column k+1 (already updated above) into the other buffer.
        // Compile-time-c cndmask selection — NO dynamic index into acc.
        const int kn = k + 1;
        if (kn < NREP && ((kn >> 2) & 15) == tj) {
            const int csel = ((kn >> 6) << 2) | (kn & 3);
            float* nxt = col[kn & 1];
            float v[8];
            #pragma unroll
            for (int r = 0; r < 8; ++r) v[r] = acc[r][0];
            #pragma unroll
            for (int c = 1; c < 8; ++c) {
                const bool m = (c == csel);
                #pragma unroll
                for (int r = 0; r < 8; ++r) v[r] = m ? acc[r][c] : v[r];
            }
            #pragma unroll
            for (int r = 0; r < 8; ++r) nxt[i0 + r] = v[r];
        }
        __syncthreads();
    }

    // --- epilogue: L[i][j] = c_ij / sqrt(c_jj), zeros above diagonal ---
    float* lout = out_l + (size_t)loc * (NREP * NREP);
    #pragma unroll
    for (int r = 0; r < 8; ++r) {
        const int i = i0 + r;
        #pragma unroll
        for (int g = 0; g < 2; ++g) {
            float tmp[4];
            #pragma unroll
            for (int e = 0; e < 4; ++e) {
                const int j = j00 + 64 * g + e;
                const int c = g * 4 + e;
                tmp[e] = (i >= j) ? acc[r][c] * rs[j] : 0.0f;
            }
            float4 v = make_float4(tmp[0], tmp[1], tmp[2], tmp[3]);
            *(float4*)(lout + (size_t)i * NREP + j00 + 64 * g) = v;
        }
    }
}

extern "C" void kernel_launch(void* const* d_in, const int* in_sizes, int n_in,
                              void* d_out, int out_size, void* d_ws, size_t ws_size,
                              hipStream_t stream) {
    const float* aug    = (const float*)d_in[0];
    const float* theta  = (const float*)d_in[1];
    const float* scales = (const float*)d_in[2];
    const float* nug    = (const float*)d_in[3];
    const int*   bidx   = (const int*)d_in[4];
    float* g = (float*)d_out;
    float* l = g + (size_t)NLOC * NREP * NREP;
    hipLaunchKernelGGL(otm_fused, dim3(NLOC), dim3(256), 0, stream,
                       aug, theta, scales, nug, bidx, g, l);
}